// Round 1
// 785.026 us; speedup vs baseline: 1.0241x; 1.0241x over previous
//
#include <hip/hip_runtime.h>
#include <math.h>

#define B    64
#define T    4096
#define DENC 512
#define DDEC 512
#define DATT 256

#define BM   128
#define BK   32
#define NCH  (T / BM)   // 32 t-chunks per batch row

typedef __attribute__((ext_vector_type(8))) short short8;
typedef __attribute__((ext_vector_type(4))) float f32x4;

// float -> bf16, round-to-nearest-even (tiny one-shot kernels only)
__device__ __forceinline__ unsigned short f2bf(float f) {
    union { float f; unsigned u; } v; v.f = f;
    return (unsigned short)((v.u + 0x7fffu + ((v.u >> 16) & 1u)) >> 16);
}

// two f32 -> packed bf16 pair (round-half-up): 2 adds + 1 v_perm_b32
__device__ __forceinline__ unsigned pk2bf(float a, float b) {
    unsigned ua = __float_as_uint(a) + 0x8000u;
    unsigned ub = __float_as_uint(b) + 0x8000u;
    return __builtin_amdgcn_perm(ub, ua, 0x07060302u);
}

__device__ __forceinline__ float tanh_fast(float x) {
    float e = __expf(2.0f * x);
    return 1.0f - 2.0f / (e + 1.0f);
}

// ---------------------------------------------------------------------------
// K_prep (merged): blocks 0..127   : Wk_w f32 -> bf16 workspace (k_wkconv)
//                  blocks 128..383 : qq[b,a] = Wq_w[a,:]·h_dec[b,:] + Wq_b + Wk_b
//                                    (256 blocks: 4 per batch, 4 threads/output
//                                     -> 4x shorter serial load chain than the
//                                     old 64-block version)
// ---------------------------------------------------------------------------
__global__ __launch_bounds__(256) void k_prep(const float* __restrict__ Wk_w,
                                              unsigned short* __restrict__ WkB,
                                              const float* __restrict__ h_dec,
                                              const float* __restrict__ Wq_w,
                                              const float* __restrict__ Wq_b,
                                              const float* __restrict__ Wk_b,
                                              float* __restrict__ qq) {
    __shared__ float sh[DDEC];
    const int blk = blockIdx.x;
    const int tid = threadIdx.x;

    if (blk < 128) {
        // ---- weight conversion: 128*256*4 = 131072 = DATT*DENC elems ----
        int i = (blk * 256 + tid) * 4;
        float4 v = *(const float4*)(Wk_w + i);
        ushort4 o;
        o.x = f2bf(v.x); o.y = f2bf(v.y); o.z = f2bf(v.z); o.w = f2bf(v.w);
        *(ushort4*)(WkB + i) = o;
        return;
    }

    // ---- q projection ----
    const int q  = blk - 128;       // 0..255
    const int b  = q >> 2;          // 0..63
    const int a0 = (q & 3) * 64;    // 64 outputs per block

    ((float2*)sh)[tid] = ((const float2*)(h_dec + (size_t)b * DDEC))[tid];
    __syncthreads();

    const int a    = a0 + (tid >> 2);  // output attention dim
    const int part = tid & 3;          // quarter of the DDEC reduction
    const float4* wr  = (const float4*)(Wq_w + (size_t)a * DDEC + part * 128);
    const float4* shv = (const float4*)sh + part * 32;
    float acc = 0.f;
#pragma unroll 8
    for (int i = 0; i < 32; ++i) {
        float4 wv = wr[i];
        float4 hv = shv[i];
        acc += wv.x * hv.x + wv.y * hv.y + wv.z * hv.z + wv.w * hv.w;
    }
    // reduce the quad (lanes 4k..4k+3 of one wave)
    acc += __shfl_xor(acc, 1, 64);
    acc += __shfl_xor(acc, 2, 64);
    if (part == 0) qq[b * DATT + a] = acc + Wq_b[a] + Wk_b[a];
}

// ---------------------------------------------------------------------------
// K2 (fused): per (t-chunk, b) block — UNCHANGED proven structure:
//   phase 1: bf16 MFMA score GEMM
//   phase 2: masked scores -> global; block-local online-softmax partial
//   phase 3: ctx_part[e] = sum_t p_t * h_enc[t][e] (L2/L3 tile re-read)
// ---------------------------------------------------------------------------
__global__ __launch_bounds__(256, 2) void k_fused(const float* __restrict__ h_enc,
                                                  const unsigned short* __restrict__ WkB,
                                                  const float* __restrict__ qq,
                                                  const float* __restrict__ v_w,
                                                  const int* __restrict__ mask,
                                                  float* __restrict__ scores,
                                                  float* __restrict__ part_m,
                                                  float* __restrict__ part_l,
                                                  float* __restrict__ part_ctx) {
    __shared__ short As[BM * BK];    // 8 KB
    __shared__ short Bs[DATT * BK];  // 16 KB
    __shared__ float sp[2][BM];
    __shared__ float ps[BM];
    __shared__ float red_a[4], red_b[4];

    const int tc   = blockIdx.x;
    const int b    = blockIdx.y;
    const int tid  = threadIdx.x;
    const int wv   = tid >> 6;
    const int lane = tid & 63;
    const int ln15 = lane & 15;
    const int qd   = lane >> 4;
    const int wv_t = wv >> 1;
    const int wv_a = wv & 1;
    const int t0   = tc * BM;

    f32x4 acc[4][8];
#pragma unroll
    for (int i = 0; i < 4; ++i)
#pragma unroll
        for (int j = 0; j < 8; ++j) acc[i][j] = (f32x4){0.f, 0.f, 0.f, 0.f};

    const float* Abase = h_enc + ((size_t)b * T + t0) * DENC;

    for (int k0 = 0; k0 < DENC; k0 += BK) {
        // ---- B tile: async bf16 global->LDS, 4 x 16B chunks per thread ----
#pragma unroll
        for (int it = 0; it < 4; ++it) {
            int idx = (wv * 4 + it) * 64 + lane;
            int r   = idx >> 2;
            int cc  = (idx & 3) ^ ((r >> 1) & 3);
            const unsigned short* gp = WkB + (size_t)r * DENC + k0 + cc * 8;
            short* lp = &Bs[(wv * 4 + it) * 64 * 8];
            __builtin_amdgcn_global_load_lds(
                (const __attribute__((address_space(1))) unsigned int*)gp,
                (__attribute__((address_space(3))) unsigned int*)lp, 16, 0, 0);
        }
        // ---- A tile: f32 load, packed cvt, ds_write_b128 (swizzled) ----
#pragma unroll
        for (int it = 0; it < 2; ++it) {
            int idx = it * 256 + tid;
            int r   = idx >> 2;
            int cc  = (idx & 3) ^ ((r >> 1) & 3);
            const float* gp = Abase + (size_t)r * DENC + k0 + cc * 8;
            float4 v0 = *(const float4*)gp;
            float4 v1 = *(const float4*)(gp + 4);
            uint4 pk;
            pk.x = pk2bf(v0.x, v0.y);
            pk.y = pk2bf(v0.z, v0.w);
            pk.z = pk2bf(v1.x, v1.y);
            pk.w = pk2bf(v1.z, v1.w);
            *(uint4*)&As[idx * 8] = pk;
        }
        __syncthreads();

        // ---- fragments + MFMA ----
        short8 af[4], bfr[8];
#pragma unroll
        for (int ti = 0; ti < 4; ++ti) {
            int r = wv_t * 64 + ti * 16 + ln15;
            int s = qd ^ ((r >> 1) & 3);
            af[ti] = *(const short8*)&As[r * 32 + s * 8];
        }
#pragma unroll
        for (int tj = 0; tj < 8; ++tj) {
            int r = wv_a * 128 + tj * 16 + ln15;
            int s = qd ^ ((r >> 1) & 3);
            bfr[tj] = *(const short8*)&Bs[r * 32 + s * 8];
        }
#pragma unroll
        for (int ti = 0; ti < 4; ++ti)
#pragma unroll
            for (int tj = 0; tj < 8; ++tj)
                acc[ti][tj] = __builtin_amdgcn_mfma_f32_16x16x32_bf16(
                    af[ti], bfr[tj], acc[ti][tj], 0, 0, 0);
        __syncthreads();
    }

    // ---- epilogue: s[t] = sum_a v[a]*tanh(qq[a] + k[t,a]) ----
    float qr[8], vr[8];
#pragma unroll
    for (int tj = 0; tj < 8; ++tj) {
        int a = wv_a * 128 + tj * 16 + ln15;
        qr[tj] = qq[b * DATT + a];
        vr[tj] = v_w[a];
    }
#pragma unroll
    for (int ti = 0; ti < 4; ++ti) {
#pragma unroll
        for (int rg = 0; rg < 4; ++rg) {
            float s = 0.f;
#pragma unroll
            for (int tj = 0; tj < 8; ++tj)
                s += vr[tj] * tanh_fast(qr[tj] + acc[ti][tj][rg]);
            s += __shfl_xor(s, 1, 64);
            s += __shfl_xor(s, 2, 64);
            s += __shfl_xor(s, 4, 64);
            s += __shfl_xor(s, 8, 64);
            if (ln15 == 0)
                sp[wv_a][wv_t * 64 + ti * 16 + qd * 4 + rg] = s;
        }
    }
    __syncthreads();

    // ---- phase 2: masked scores + block-local softmax partial ----
    if (tid < BM) {
        int t = t0 + tid;
        float s = sp[0][tid] + sp[1][tid];
        bool mk = mask[(size_t)b * T + t] != 0;
        s = mk ? s : -1e9f;
        scores[(size_t)b * T + t] = s;
        ps[tid] = s;
    }
    __syncthreads();

    float mv = (tid < BM) ? ps[tid] : -INFINITY;
#pragma unroll
    for (int off = 32; off >= 1; off >>= 1) mv = fmaxf(mv, __shfl_xor(mv, off, 64));
    if (lane == 0) red_a[wv] = mv;
    __syncthreads();
    const float M = fmaxf(fmaxf(red_a[0], red_a[1]), fmaxf(red_a[2], red_a[3]));

    float p = 0.f;
    if (tid < BM) { p = __expf(ps[tid] - M); ps[tid] = p; }
    float ls = p;
#pragma unroll
    for (int off = 32; off >= 1; off >>= 1) ls += __shfl_xor(ls, off, 64);
    if (lane == 0) red_b[wv] = ls;
    __syncthreads();
    if (tid == 0) {
        part_m[b * NCH + tc] = M;
        part_l[b * NCH + tc] = red_b[0] + red_b[1] + red_b[2] + red_b[3];
    }

    // ---- phase 3: ctx_part[e] = sum_t p_t * h_enc[t][e] (tile re-read) ----
    const float2* hp = (const float2*)(Abase) + tid;  // e = 2*tid, 2*tid+1
    float ax = 0.f, ay = 0.f;
#pragma unroll 8
    for (int t = 0; t < BM; ++t) {
        float pt = ps[t];
        float2 hv = hp[(size_t)t * (DENC / 2)];
        ax = fmaf(pt, hv.x, ax);
        ay = fmaf(pt, hv.y, ay);
    }
    float2* pc = (float2*)(part_ctx + ((size_t)(b * NCH + tc)) * DENC) + tid;
    *pc = make_float2(ax, ay);
}

// ---------------------------------------------------------------------------
// K_final (merged combine + w): block b
//   - combine NCH partials -> ctx[b,:], M_b, 1/L_b (all in registers/LDS)
//   - w[b,t] = exp(scores[b,t] - M_b) * invL_b   (no ml round-trip)
// ---------------------------------------------------------------------------
__global__ __launch_bounds__(256) void k_final(const float* __restrict__ part_m,
                                               const float* __restrict__ part_l,
                                               const float* __restrict__ part_ctx,
                                               const float* __restrict__ scores,
                                               float* __restrict__ ctx,
                                               float* __restrict__ w) {
    const int b = blockIdx.x;
    const int tid = threadIdx.x;
    __shared__ float sm[NCH], sl[NCH];
    if (tid < NCH) {
        sm[tid] = part_m[b * NCH + tid];
        sl[tid] = part_l[b * NCH + tid];
    }
    __syncthreads();
    float M = -INFINITY;
#pragma unroll
    for (int i = 0; i < NCH; ++i) M = fmaxf(M, sm[i]);

    float L = 0.f, ax = 0.f, ay = 0.f;
    const float2* pc = (const float2*)(part_ctx + (size_t)b * NCH * DENC) + tid;
#pragma unroll 4
    for (int i = 0; i < NCH; ++i) {
        float sc = __expf(sm[i] - M);
        L += sl[i] * sc;
        float2 v = pc[(size_t)i * (DENC / 2)];
        ax = fmaf(sc, v.x, ax);
        ay = fmaf(sc, v.y, ay);
    }
    const float inv = 1.f / L;
    ((float2*)(ctx + b * DENC))[tid] = make_float2(ax * inv, ay * inv);

    // ---- w for this batch row: 4096 scores, 4 x float4 per thread ----
#pragma unroll
    for (int j = 0; j < 4; ++j) {
        size_t off = (size_t)b * T + j * 1024 + tid * 4;
        float4 s = *(const float4*)(scores + off);
        float4 o;
        o.x = __expf(s.x - M) * inv;
        o.y = __expf(s.y - M) * inv;
        o.z = __expf(s.z - M) * inv;
        o.w = __expf(s.w - M) * inv;
        *(float4*)(w + off) = o;
    }
}

// ---------------------------------------------------------------------------
extern "C" void kernel_launch(void* const* d_in, const int* in_sizes, int n_in,
                              void* d_out, int out_size, void* d_ws, size_t ws_size,
                              hipStream_t stream) {
    const float* h_enc = (const float*)d_in[0];
    const float* h_dec = (const float*)d_in[1];
    const float* Wq_w  = (const float*)d_in[2];
    const float* Wq_b  = (const float*)d_in[3];
    const float* Wk_w  = (const float*)d_in[4];
    const float* Wk_b  = (const float*)d_in[5];
    const float* v_w   = (const float*)d_in[6];
    const int*   mask  = (const int*)d_in[7];

    float* out = (float*)d_out;
    float* ctx = out;               // [B, DENC]
    float* wts = out + B * DENC;    // [B, T]

    char* ws = (char*)d_ws;
    float*          qq       = (float*)ws;                       // 64 KB
    unsigned short* WkB      = (unsigned short*)(ws + (64 << 10));   // 256 KB
    float*          scores   = (float*)(ws + (1 << 20));             // 1 MB
    float*          part_m   = (float*)(ws + (2 << 20));             // 8 KB
    float*          part_l   = (float*)(ws + (2 << 20) + (16 << 10));
    float*          part_ctx = (float*)(ws + (3 << 20));             // 4 MB

    k_prep<<<384, 256, 0, stream>>>(Wk_w, WkB, h_dec, Wq_w, Wq_b, Wk_b, qq);
    k_fused<<<dim3(NCH, B), 256, 0, stream>>>(h_enc, WkB, qq, v_w, mask,
                                              scores, part_m, part_l, part_ctx);
    k_final<<<B, 256, 0, stream>>>(part_m, part_l, part_ctx, scores, ctx, wts);
}